// Round 1
// 266.310 us; speedup vs baseline: 1.0161x; 1.0161x over previous
//
#include <hip/hip_runtime.h>
#include <math.h>

// One 16-lane group per ray (4 rays per 64-lane wave). Slab-test the ray
// against the AABB to find the only sample interval that can have nonzero
// alpha; everything outside has sigma*inbbox == 0 exactly and
// (1 - 0 + 1e-10) rounds to 1.0f in fp32, so transmittance is unchanged ->
// skip those sigma/rgb reads entirely (~96%).
//
// 16 lanes/ray (vs 64) because active ranges are only ~40-82 samples:
// 4x fewer waves, 4-step prefix product instead of 6, less idle-lane work.
#define LPR 16  // lanes per ray (power of 2, <= 64)

__global__ __launch_bounds__(256) void nerf_fused(
    const float* __restrict__ rays_o,
    const float* __restrict__ rays_d,
    const float* __restrict__ sigma_feat,
    const float* __restrict__ rgb,
    const float* __restrict__ aabb,
    float* __restrict__ out,
    int N, int S)
{
    const int ray  = (int)((blockIdx.x * (unsigned)blockDim.x + threadIdx.x) / LPR);
    const int lane = threadIdx.x & (LPR - 1);
    if (ray >= N) return;

    const float ox = rays_o[ray*3+0], oy = rays_o[ray*3+1], oz = rays_o[ray*3+2];
    const float dx = rays_d[ray*3+0], dy = rays_d[ray*3+1], dz = rays_d[ray*3+2];
    const float blo0 = aabb[0], blo1 = aabb[1], blo2 = aabb[2];
    const float bhi0 = aabb[3], bhi1 = aabb[4], bhi2 = aabb[5];

    const double h = 4.0 / (double)(S - 1);   // linspace step (f64, cast per sample)

    // ---- conservative slab test on [NEAR, FAR] ----
    float tmin = 2.0f, tmax = 6.0f;
    bool empty = false;
    {
        const float oc[3] = {ox, oy, oz};
        const float dc[3] = {dx, dy, dz};
        const float lo[3] = {blo0, blo1, blo2};
        const float hi[3] = {bhi0, bhi1, bhi2};
        #pragma unroll
        for (int c = 0; c < 3; ++c) {
            float d = dc[c], o = oc[c];
            if (d == 0.0f) {
                if (o < lo[c] || o > hi[c]) empty = true;
            } else {
                float t0 = (lo[c] - o) / d;
                float t1 = (hi[c] - o) / d;
                float a = fminf(t0, t1), b = fmaxf(t0, t1);
                tmin = fmaxf(tmin, a);
                tmax = fminf(tmax, b);
            }
        }
    }
    int s0 = 0, s1 = 0;
    if (!empty && tmin <= tmax) {
        float inv_h = (float)(1.0 / h);
        s0 = (int)floorf((tmin - 2.0f) * inv_h) - 2;   // pad 2 samples each side;
        s1 = (int)ceilf ((tmax - 2.0f) * inv_h) + 3;   // exact per-sample test inside
        s0 = s0 < 0 ? 0 : s0;
        s1 = s1 > S ? S : s1;
        if (s1 < s0) s1 = s0;
    }

    float T  = 1.0f;           // running transmittance (skipped samples multiply by exactly 1.0f)
    float ar = 0.0f, ag = 0.0f, ab = 0.0f, ad = 0.0f;

    const float* __restrict__ sfeat = sigma_feat + (size_t)ray * S;
    const float* __restrict__ rgbp  = rgb + (size_t)ray * S * 3;

    for (int base = s0; base < s1; base += LPR) {
        int s = base + lane;
        bool active = (s < s1);
        float alpha = 0.0f, tf = 0.0f;
        if (active) {
            tf = (float)(2.0 + (double)s * h);
            float dist;
            if (s == S - 1) {
                float tp = (float)(2.0 + (double)(s - 1) * h);
                dist = (tf - tp) * 25.0f;            // last dist duplicated, *DISTANCE_SCALE
            } else {
                float tn = (float)(2.0 + (double)(s + 1) * h);
                dist = (tn - tf) * 25.0f;
            }
            // match numpy's  o + d*t  (mul then add, no fma contraction)
            float px = __fadd_rn(ox, __fmul_rn(dx, tf));
            float py = __fadd_rn(oy, __fmul_rn(dy, tf));
            float pz = __fadd_rn(oz, __fmul_rn(dz, tf));
            bool inb = (px >= blo0) & (px <= bhi0) &
                       (py >= blo1) & (py <= bhi1) &
                       (pz >= blo2) & (pz <= bhi2);
            if (inb) {
                float x = sfeat[s] - 10.0f;          // DENSITY_SHIFT
                // stable softplus = max(x,0) + log1p(exp(-|x|))
                float sp = (x > 0.0f) ? (x + __logf(1.0f + __expf(-x)))
                                      : __logf(1.0f + __expf(x));
                alpha = 1.0f - __expf(-sp * dist);
            }
        }
        // per-lane factor; 16-lane inclusive prefix product (within the ray's group)
        float f = active ? ((1.0f - alpha) + 1e-10f) : 1.0f;
        float p = f;
        #pragma unroll
        for (int off = 1; off < LPR; off <<= 1) {
            float q = __shfl_up(p, off, LPR);
            if (lane >= off) p *= q;
        }
        float pe = __shfl_up(p, 1, LPR);  // exclusive prefix
        if (lane == 0) pe = 1.0f;
        float w = alpha * (T * pe);
        if (w != 0.0f) {                  // only touch rgb where weight is nonzero
            const float* rp = rgbp + (size_t)s * 3;
            ar = fmaf(w, rp[0], ar);
            ag = fmaf(w, rp[1], ag);
            ab = fmaf(w, rp[2], ab);
            ad = fmaf(w, tf,    ad);
        }
        T *= __shfl(p, LPR - 1, LPR);     // carry total product into next chunk
    }

    // 16-lane butterfly reduction within the ray's group
    #pragma unroll
    for (int off = LPR / 2; off > 0; off >>= 1) {
        ar += __shfl_xor(ar, off, LPR);
        ag += __shfl_xor(ag, off, LPR);
        ab += __shfl_xor(ab, off, LPR);
        ad += __shfl_xor(ad, off, LPR);
    }

    if (lane == 0) {
        out[(size_t)ray * 3 + 0] = ar;          // rgb_map
        out[(size_t)ray * 3 + 1] = ag;
        out[(size_t)ray * 3 + 2] = ab;
        out[(size_t)N * 3 + ray] = ad;          // depth_map
        out[(size_t)N * 4 + ray] = T;           // bg_weight
    }
}

extern "C" void kernel_launch(void* const* d_in, const int* in_sizes, int n_in,
                              void* d_out, int out_size, void* d_ws, size_t ws_size,
                              hipStream_t stream) {
    const float* rays_o     = (const float*)d_in[0];
    const float* rays_d     = (const float*)d_in[1];
    const float* sigma_feat = (const float*)d_in[2];
    const float* rgb        = (const float*)d_in[3];
    const float* aabb       = (const float*)d_in[4];
    float* out = (float*)d_out;

    const int N = in_sizes[0] / 3;        // 32768
    const int S = in_sizes[2] / N;        // 512

    const int threads = 256;              // 4 waves; 16 rays per block
    const int blocks  = (N * LPR + threads - 1) / threads;   // 2048
    hipLaunchKernelGGL(nerf_fused, dim3(blocks), dim3(threads), 0, stream,
                       rays_o, rays_d, sigma_feat, rgb, aabb, out, N, S);
}